// Round 4
// baseline (241.829 us; speedup 1.0000x reference)
//
#include <hip/hip_runtime.h>
#include <hip/hip_bf16.h>
#include <math.h>

#define B_ 64
#define L_ 512
#define D_ 768
#define H_ 384
#define T_ 9
#define M_ (B_ * L_)   // 32768 rows

typedef __attribute__((ext_vector_type(8))) short short8;
typedef __attribute__((ext_vector_type(4))) float f32x4;

__device__ __forceinline__ float gelu_exact(float x) {
    return 0.5f * x * (1.0f + erff(x * 0.70710678118654752440f));
}

__device__ __forceinline__ unsigned short f2bf(float f) {
    unsigned u = __float_as_uint(f);
    u += 0x7FFFu + ((u >> 16) & 1u);   // RNE
    return (unsigned short)(u >> 16);
}

__device__ __forceinline__ float wredf(float v) {
#pragma unroll
    for (int m = 32; m >= 1; m >>= 1) v += __shfl_xor(v, m, 64);
    return v;
}

// CK-style LDS-only barrier: waits lgkmcnt(0) but leaves global loads (vmcnt)
// in flight across the barrier — this is what __syncthreads() cannot express.
__device__ __forceinline__ void sync_lds() {
    asm volatile("s_waitcnt lgkmcnt(0)\n\ts_barrier" ::: "memory");
}

// -----------------------------------------------------------------------------
// Kernel 0: build fragment-ordered bf16 weights + zero d_out.
//   W1F[((nt*24 + kc)*64 + lane)*8 + j] = W1[kc*32 + q*8 + j][nt*16 + lm]
//   W2F[(kk*64 + lane)*8 + j]           = (lm<9) ? W2[kk*32 + q*8 + j][lm] : 0
// -----------------------------------------------------------------------------
__global__ __launch_bounds__(256) void prep_kernel(
    const float* __restrict__ W1, const float* __restrict__ W2,
    unsigned short* __restrict__ W1F, unsigned short* __restrict__ W2F,
    float* __restrict__ out)
{
    if (blockIdx.x == 0 && threadIdx.x == 0) out[0] = 0.f;
    const int g    = blockIdx.x * 4 + (threadIdx.x >> 6);
    const int lane = threadIdx.x & 63;
    const int lm   = lane & 15;
    const int q    = lane >> 4;
    if (g < 576) {                       // W1F: g = nt*24 + kc
        const int nt = g / 24;
        const int kc = g - nt * 24;
        const int n  = nt * 16 + lm;
        short8 v;
#pragma unroll
        for (int j = 0; j < 8; ++j)
            v[j] = (short)f2bf(W1[(size_t)(kc * 32 + q * 8 + j) * H_ + n]);
        *(short8*)(W1F + ((size_t)g * 64 + lane) * 8) = v;
    } else if (g < 588) {                // W2F: kk = g - 576
        const int kk = g - 576;
        short8 v;
#pragma unroll
        for (int j = 0; j < 8; ++j) {
            int k = kk * 32 + q * 8 + j;
            v[j] = (lm < 9) ? (short)f2bf(W2[(size_t)k * T_ + lm]) : (short)0;
        }
        *(short8*)(W2F + ((size_t)kk * 64 + lane) * 8) = v;
    }
}

// -----------------------------------------------------------------------------
// Kernel 1: emissions = gelu(X @ W1 + b1) @ W2 + b2.
// BM=64, 256 thr, grid 512. 2-iteration-deep global prefetch (X and B) kept in
// flight ACROSS the LDS-only barrier (sync_lds). K-loop fully unrolled so the
// double-buffer slot indices are compile-time (no scratch).
// -----------------------------------------------------------------------------
__global__ __launch_bounds__(256, 2) void emis_mfma_kernel(
    const float* __restrict__ X,             // [M_][768] fp32
    const unsigned short* __restrict__ W1F,  // fragment-ordered bf16
    const float* __restrict__ b1,            // [384]
    const unsigned short* __restrict__ W2F,  // fragment-ordered bf16
    const float* __restrict__ b2,            // [9]
    float* __restrict__ em)                  // [M_][9]
{
    __shared__ unsigned short Hs[64 * 392];  // 50176 B; head doubles as As[2]
    unsigned short* As = Hs;                 // As[buf] at buf*2560 shorts, row stride 40

    const int t    = threadIdx.x;
    const int lane = t & 63;
    const int w    = t >> 6;        // wave = n-group (96 cols)
    const int lm   = lane & 15;
    const int q    = lane >> 4;
    const int row0 = blockIdx.x * 64;

    const int ar  = t >> 2;         // staging row 0..63
    const int ako = (t & 3) << 3;   // staging k-offset 0,8,16,24
    const float* xp = X + (size_t)(row0 + ar) * D_ + ako;

    f32x4 acc[4][6];
#pragma unroll
    for (int mt = 0; mt < 4; ++mt)
#pragma unroll
        for (int i = 0; i < 6; ++i) acc[mt][i] = (f32x4)0.f;

    // ---- prologue ----
    // tile 0 -> LDS buf0 directly
    {
        float4 p0 = *(const float4*)(xp);
        float4 p1 = *(const float4*)(xp + 4);
        short8 v;
        v[0] = (short)f2bf(p0.x); v[1] = (short)f2bf(p0.y);
        v[2] = (short)f2bf(p0.z); v[3] = (short)f2bf(p0.w);
        v[4] = (short)f2bf(p1.x); v[5] = (short)f2bf(p1.y);
        v[6] = (short)f2bf(p1.z); v[7] = (short)f2bf(p1.w);
        *(short8*)&As[ar * 40 + ako] = v;
    }
    // X pipeline: xv[kc&1] holds tile kc+1 at iter kc
    float4 xv[2][2];
    xv[0][0] = *(const float4*)(xp + 32);  xv[0][1] = *(const float4*)(xp + 36);
    xv[1][0] = *(const float4*)(xp + 64);  xv[1][1] = *(const float4*)(xp + 68);
    // B pipeline: bb[kc&1] holds tile kc at iter kc
    short8 bb[2][6];
#pragma unroll
    for (int i = 0; i < 6; ++i) {
        bb[0][i] = *(const short8*)(W1F + (((size_t)(w * 6 + i) * 24 + 0) * 64 + lane) * 8);
        bb[1][i] = *(const short8*)(W1F + (((size_t)(w * 6 + i) * 24 + 1) * 64 + lane) * 8);
    }

#pragma unroll
    for (int kc = 0; kc < 24; ++kc) {
        const int s = kc & 1;
        sync_lds();                          // As[s] visible; vmcnt NOT drained
        short8 af[4];
#pragma unroll
        for (int mt = 0; mt < 4; ++mt)
            af[mt] = *(const short8*)&As[s * 2560 + (mt * 16 + lm) * 40 + (q << 3)];
#pragma unroll
        for (int mt = 0; mt < 4; ++mt)
#pragma unroll
            for (int i = 0; i < 6; ++i)
                acc[mt][i] = __builtin_amdgcn_mfma_f32_16x16x32_bf16(
                    af[mt], bb[s][i], acc[mt][i], 0, 0, 0);
        if (kc < 23) {
            // consume xv[s] = tile kc+1 -> bf16 -> As[s^1]
            float4 x0 = xv[s][0], x1 = xv[s][1];
            short8 v;
            v[0] = (short)f2bf(x0.x); v[1] = (short)f2bf(x0.y);
            v[2] = (short)f2bf(x0.z); v[3] = (short)f2bf(x0.w);
            v[4] = (short)f2bf(x1.x); v[5] = (short)f2bf(x1.y);
            v[6] = (short)f2bf(x1.z); v[7] = (short)f2bf(x1.w);
            *(short8*)&As[(s ^ 1) * 2560 + ar * 40 + ako] = v;
            if (kc < 21) {   // refill X with tile kc+3
                xv[s][0] = *(const float4*)(xp + (kc + 3) * 32);
                xv[s][1] = *(const float4*)(xp + (kc + 3) * 32 + 4);
            }
            if (kc < 22) {   // refill B with tile kc+2
#pragma unroll
                for (int i = 0; i < 6; ++i)
                    bb[s][i] = *(const short8*)(W1F +
                        (((size_t)(w * 6 + i) * 24 + kc + 2) * 64 + lane) * 8);
            }
        }
    }
    __syncthreads();   // full drain once; safe to reuse Hs region

    // ---- epilogue A: +b1, gelu, h -> Hs (bf16, row stride 392) ----
#pragma unroll
    for (int i = 0; i < 6; ++i) {
        const int col = w * 96 + i * 16 + lm;
        const float b1v = b1[col];
#pragma unroll
        for (int mt = 0; mt < 4; ++mt)
#pragma unroll
            for (int r = 0; r < 4; ++r) {
                float h = gelu_exact(acc[mt][i][r] + b1v);
                Hs[(mt * 16 + q * 4 + r) * 392 + col] = f2bf(h);
            }
    }
    __syncthreads();

    // ---- epilogue B: em = h @ W2 via MFMA; wave w handles m-tile w ----
    f32x4 e = (f32x4)0.f;
#pragma unroll
    for (int kk = 0; kk < 12; ++kk) {
        short8 ah = *(const short8*)&Hs[(w * 16 + lm) * 392 + kk * 32 + (q << 3)];
        short8 bw = *(const short8*)(W2F + ((size_t)(kk * 64 + lane)) * 8);
        e = __builtin_amdgcn_mfma_f32_16x16x32_bf16(ah, bw, e, 0, 0, 0);
    }
    if (lm < 9) {
        const float b2v = b2[lm];
#pragma unroll
        for (int r = 0; r < 4; ++r)
            em[(size_t)(row0 + w * 16 + q * 4 + r) * T_ + lm] = e[r] + b2v;
    }
}

// -----------------------------------------------------------------------------
// Kernel 2: CRF chunked log-semiring scan. 64 blocks x 288 threads.
// Phase A: lane (c,i), c in [0,32), computes row i of chunk c's 9x9 transfer
// matrix over 16 steps; transitions in 81 REGISTERS (256-VGPR budget at 288
// threads — no spills). Phase B: wave 0 combines 32 matrices; wave 1 computes
// the numerator. Result atomically accumulated into d_out (prep zeroed it).
// -----------------------------------------------------------------------------
__global__ __launch_bounds__(288) void crf_kernel(
    const float* __restrict__ em,
    const int* __restrict__ labels,
    const unsigned char* __restrict__ maskb,
    const float* __restrict__ st,
    const float* __restrict__ et,
    const float* __restrict__ tr,
    float* __restrict__ out)
{
    const int b = blockIdx.x;
    const int t = threadIdx.x;

    __shared__ float es[32 * 145];   // es[c*145 + s*9 + j], 16 steps/chunk
    __shared__ float Ms[32 * 81];
    __shared__ float trs[81];
    __shared__ float red[2];
    __shared__ unsigned char msh[L_];
    __shared__ int lbs[L_];

    const int mstride =
        (maskb[0] != 0 && maskb[1] == 0 && maskb[2] == 0 && maskb[3] == 0) ? 4 : 1;

    const float* eb = em + (size_t)b * L_ * T_;
    for (int i = t; i < L_ * T_; i += 288) {
        int tt = i / T_, j = i - tt * T_;
        es[(tt >> 4) * 145 + (tt & 15) * 9 + j] = eb[i];
    }
    if (t < 81) trs[t] = tr[t];
    for (int i = t; i < L_; i += 288) {
        msh[i] = maskb[((size_t)b * L_ + i) * (size_t)mstride];
        lbs[i] = labels[b * L_ + i];
    }
    __syncthreads();

    // ---- Phase A: per-chunk transfer matrices (16 steps each) ----
    {
        const int c  = t / 9;          // 0..31
        const int i0 = t - c * 9;
        float trr[81];
#pragma unroll
        for (int i = 0; i < 81; ++i) trr[i] = trs[i];
        float V[9];
#pragma unroll
        for (int j = 0; j < 9; ++j) V[j] = (j == i0) ? 0.f : -1e30f;

        const int sbeg = (c == 0) ? 1 : 0;
        for (int s = sbeg; s < 16; ++s) {
            int tt = c * 16 + s;
            if (msh[tt]) {
                const float* ep = &es[c * 145 + s * 9];
                float nv[9];
#pragma unroll
                for (int j = 0; j < 9; ++j) {
                    float a[9];
#pragma unroll
                    for (int k = 0; k < 9; ++k) a[k] = V[k] + trr[k * 9 + j];
                    float mx = a[0];
#pragma unroll
                    for (int k = 1; k < 9; ++k) mx = fmaxf(mx, a[k]);
                    float sum = 0.f;
#pragma unroll
                    for (int k = 0; k < 9; ++k) sum += __expf(a[k] - mx);
                    nv[j] = ep[j] + mx + __logf(sum);
                }
#pragma unroll
                for (int j = 0; j < 9; ++j) V[j] = nv[j];
            }
        }
#pragma unroll
        for (int j = 0; j < 9; ++j) Ms[c * 81 + i0 * 9 + j] = V[j];
    }
    __syncthreads();

    const int lane = t & 63;
    const int w    = t >> 6;
    if (w == 0) {
        // ---- Phase B: combine 32 chunk matrices ----
        const int jj = lane < 9 ? lane : 8;
        float alpha = (lane < 9) ? st[jj] + es[jj] : -1e30f;
        for (int c = 0; c < 32; ++c) {
            float a[9];
#pragma unroll
            for (int i = 0; i < 9; ++i) {
                float av = __shfl(alpha, i, 64);
                a[i] = av + Ms[c * 81 + i * 9 + jj];
            }
            float mx = a[0];
#pragma unroll
            for (int i = 1; i < 9; ++i) mx = fmaxf(mx, a[i]);
            float sum = 0.f;
#pragma unroll
            for (int i = 0; i < 9; ++i) sum += __expf(a[i] - mx);
            float nv = mx + __logf(sum);
            if (lane < 9) alpha = nv;
        }
        float v = (lane < 9) ? alpha + et[jj] : -1e30f;
        float mx = v;
#pragma unroll
        for (int m = 32; m >= 1; m >>= 1) mx = fmaxf(mx, __shfl_xor(mx, m, 64));
        float s = __expf(v - mx);
        s = wredf(s);
        if (lane == 0) red[0] = mx + __logf(s);   // denom
    } else if (w == 1) {
        // ---- numerator ----
        float emit_s = 0.f, tr_sc = 0.f, mcnt = 0.f;
        for (int tt = lane; tt < L_; tt += 64) {
            if (msh[tt]) {
                mcnt += 1.f;
                int tag = lbs[tt];
                emit_s += es[(tt >> 4) * 145 + (tt & 15) * 9 + tag];
                if (tt >= 1) tr_sc += trs[lbs[tt - 1] * 9 + tag];
            }
        }
        emit_s = wredf(emit_s);
        tr_sc  = wredf(tr_sc);
        mcnt   = wredf(mcnt);
        if (lane == 0) {
            int last = (int)mcnt - 1;
            red[1] = st[lbs[0]] + emit_s + tr_sc + et[lbs[last]];
        }
    }
    __syncthreads();
    if (t == 0) atomicAdd(out, (red[0] - red[1]) * (1.0f / (float)B_));
}

extern "C" void kernel_launch(void* const* d_in, const int* in_sizes, int n_in,
                              void* d_out, int out_size, void* d_ws, size_t ws_size,
                              hipStream_t stream) {
    const float*         enc    = (const float*)d_in[0];
    const int*           labels = (const int*)d_in[1];
    const unsigned char* mask   = (const unsigned char*)d_in[2];
    const float*         W1     = (const float*)d_in[3];
    const float*         b1     = (const float*)d_in[4];
    const float*         W2     = (const float*)d_in[5];
    const float*         b2     = (const float*)d_in[6];
    const float*         st     = (const float*)d_in[7];
    const float*         et     = (const float*)d_in[8];
    const float*         tr     = (const float*)d_in[9];

    float* em           = (float*)d_ws;                    // 1,179,648 B
    unsigned short* W1F = (unsigned short*)(em + (size_t)M_ * T_);  // 589,824 B
    unsigned short* W2F = W1F + (size_t)576 * 64 * 8;      // 12,288 B

    prep_kernel<<<147, 256, 0, stream>>>(W1, W2, W1F, W2F, (float*)d_out);
    emis_mfma_kernel<<<M_ / 64, 256, 0, stream>>>(enc, W1F, b1, W2F, b2, em);
    crf_kernel<<<B_, 288, 0, stream>>>(em, labels, mask, st, et, tr, (float*)d_out);
}

// Round 5
// 232.797 us; speedup vs baseline: 1.0388x; 1.0388x over previous
//
#include <hip/hip_runtime.h>
#include <hip/hip_bf16.h>
#include <math.h>

#define B_ 64
#define L_ 512
#define D_ 768
#define H_ 384
#define T_ 9
#define M_ (B_ * L_)   // 32768 rows

typedef __attribute__((ext_vector_type(8))) short short8;
typedef __attribute__((ext_vector_type(4))) float f32x4;

__device__ __forceinline__ unsigned short f2bf(float f) {
    unsigned u = __float_as_uint(f);
    u += 0x7FFFu + ((u >> 16) & 1u);   // RNE
    return (unsigned short)(u >> 16);
}

// packed f32x2 -> bf16x2 (v_cvt_pk_bf16_f32 on gfx950)
__device__ __forceinline__ unsigned pkbf2(float a, float b) {
    __hip_bfloat162 h = __float22bfloat162_rn(float2{a, b});
    return *(unsigned*)&h;
}

// tanh-form gelu as x * sigmoid(2*0.79788456*(x + 0.044715 x^3)) — 1 exp.
__device__ __forceinline__ float gelu_fast(float x) {
    float z2 = 1.5957691216f * x + 0.0713548162726f * x * x * x;
    return x / (1.f + __expf(-z2));
}

__device__ __forceinline__ float wredf(float v) {
#pragma unroll
    for (int m = 32; m >= 1; m >>= 1) v += __shfl_xor(v, m, 64);
    return v;
}

// LDS-only barrier: leaves global loads in flight across the barrier.
__device__ __forceinline__ void sync_lds() {
    asm volatile("s_waitcnt lgkmcnt(0)\n\ts_barrier" ::: "memory");
}

// -----------------------------------------------------------------------------
// Kernel 0: fragment-ordered bf16 weights + zero d_out.
//   W1F[((nt*24 + kc)*64 + lane)*8 + j] = W1[kc*32 + q*8 + j][nt*16 + lm]
//   W2F[(kk*64 + lane)*8 + j]           = (lm<9) ? W2[kk*32 + q*8 + j][lm] : 0
// -----------------------------------------------------------------------------
__global__ __launch_bounds__(256) void prep_kernel(
    const float* __restrict__ W1, const float* __restrict__ W2,
    unsigned short* __restrict__ W1F, unsigned short* __restrict__ W2F,
    float* __restrict__ out)
{
    if (blockIdx.x == 0 && threadIdx.x == 0) out[0] = 0.f;
    const int g    = blockIdx.x * 4 + (threadIdx.x >> 6);
    const int lane = threadIdx.x & 63;
    const int lm   = lane & 15;
    const int q    = lane >> 4;
    if (g < 576) {                       // W1F: g = nt*24 + kc
        const int nt = g / 24;
        const int kc = g - nt * 24;
        const int n  = nt * 16 + lm;
        short8 v;
#pragma unroll
        for (int j = 0; j < 8; ++j)
            v[j] = (short)f2bf(W1[(size_t)(kc * 32 + q * 8 + j) * H_ + n]);
        *(short8*)(W1F + ((size_t)g * 64 + lane) * 8) = v;
    } else if (g < 588) {                // W2F: kk = g - 576
        const int kk = g - 576;
        short8 v;
#pragma unroll
        for (int j = 0; j < 8; ++j) {
            int k = kk * 32 + q * 8 + j;
            v[j] = (lm < 9) ? (short)f2bf(W2[(size_t)k * T_ + lm]) : (short)0;
        }
        *(short8*)(W2F + ((size_t)kk * 64 + lane) * 8) = v;
    }
}

// -----------------------------------------------------------------------------
// Kernel 1: partial emissions. Grid 1024 = 512 row-blocks x 2 n-halves
// (blockIdx = rb + 512*half so twins share an XCD for X L2/L3 locality).
// BM=64, BN=192, 256 thr. Wave w: 4 m-tiles x 3 n-tiles = 12 MFMA/iter.
// Epilogue: gelu -> Hs -> 6 MFMA vs W2F half -> em0 (+b2) or em1.
// -----------------------------------------------------------------------------
__global__ __launch_bounds__(256) void emis_mfma_kernel(
    const float* __restrict__ X,             // [M_][768] fp32
    const unsigned short* __restrict__ W1F,
    const float* __restrict__ b1,
    const unsigned short* __restrict__ W2F,
    const float* __restrict__ b2,
    float* __restrict__ em0,                 // [M_][9] half-0 partials (+b2)
    float* __restrict__ em1)                 // [M_][9] half-1 partials
{
    __shared__ unsigned short Hs[64 * 200];  // 25600 B; head doubles as As[2]
    unsigned short* As = Hs;                 // As[buf] at buf*2560 shorts, row stride 40

    const int t    = threadIdx.x;
    const int lane = t & 63;
    const int w    = t >> 6;
    const int lm   = lane & 15;
    const int q    = lane >> 4;
    const int half = blockIdx.x >> 9;
    const int rb   = blockIdx.x & 511;
    const int row0 = rb * 64;

    const int ar  = t >> 2;
    const int ako = (t & 3) << 3;
    const float* xp = X + (size_t)(row0 + ar) * D_ + ako;

    f32x4 acc[4][3];
#pragma unroll
    for (int mt = 0; mt < 4; ++mt)
#pragma unroll
        for (int i = 0; i < 3; ++i) acc[mt][i] = (f32x4)0.f;

    const int ntg0 = half * 12 + w * 3;      // first global n-tile of this wave

    // ---- prologue ----
    {
        float4 p0 = *(const float4*)(xp);
        float4 p1 = *(const float4*)(xp + 4);
        int4 v = {(int)pkbf2(p0.x, p0.y), (int)pkbf2(p0.z, p0.w),
                  (int)pkbf2(p1.x, p1.y), (int)pkbf2(p1.z, p1.w)};
        *(int4*)&As[ar * 40 + ako] = v;
    }
    float4 xv[2][2];
    xv[0][0] = *(const float4*)(xp + 32);  xv[0][1] = *(const float4*)(xp + 36);
    xv[1][0] = *(const float4*)(xp + 64);  xv[1][1] = *(const float4*)(xp + 68);
    short8 bb[2][3];
#pragma unroll
    for (int i = 0; i < 3; ++i) {
        bb[0][i] = *(const short8*)(W1F + (((size_t)(ntg0 + i) * 24 + 0) * 64 + lane) * 8);
        bb[1][i] = *(const short8*)(W1F + (((size_t)(ntg0 + i) * 24 + 1) * 64 + lane) * 8);
    }

#pragma unroll
    for (int kc = 0; kc < 24; ++kc) {
        const int s = kc & 1;
        sync_lds();
        short8 af[4];
#pragma unroll
        for (int mt = 0; mt < 4; ++mt)
            af[mt] = *(const short8*)&As[s * 2560 + (mt * 16 + lm) * 40 + (q << 3)];
#pragma unroll
        for (int mt = 0; mt < 4; ++mt)
#pragma unroll
            for (int i = 0; i < 3; ++i)
                acc[mt][i] = __builtin_amdgcn_mfma_f32_16x16x32_bf16(
                    af[mt], bb[s][i], acc[mt][i], 0, 0, 0);
        if (kc < 23) {
            float4 x0 = xv[s][0], x1 = xv[s][1];
            int4 v = {(int)pkbf2(x0.x, x0.y), (int)pkbf2(x0.z, x0.w),
                      (int)pkbf2(x1.x, x1.y), (int)pkbf2(x1.z, x1.w)};
            *(int4*)&As[(s ^ 1) * 2560 + ar * 40 + ako] = v;
            if (kc < 21) {
                xv[s][0] = *(const float4*)(xp + (kc + 3) * 32);
                xv[s][1] = *(const float4*)(xp + (kc + 3) * 32 + 4);
            }
            if (kc < 22) {
#pragma unroll
                for (int i = 0; i < 3; ++i)
                    bb[s][i] = *(const short8*)(W1F +
                        (((size_t)(ntg0 + i) * 24 + kc + 2) * 64 + lane) * 8);
            }
        }
    }
    __syncthreads();

    // ---- epilogue A: +b1, gelu -> Hs (local cols 0..192, stride 200) ----
#pragma unroll
    for (int i = 0; i < 3; ++i) {
        const int lc = w * 48 + i * 16 + lm;
        const float b1v = b1[half * 192 + lc];
#pragma unroll
        for (int mt = 0; mt < 4; ++mt)
#pragma unroll
            for (int r = 0; r < 4; ++r) {
                float h = gelu_fast(acc[mt][i][r] + b1v);
                Hs[(mt * 16 + q * 4 + r) * 200 + lc] = f2bf(h);
            }
    }
    __syncthreads();

    // ---- epilogue B: partial em = h_half @ W2_half via 6 MFMA ----
    f32x4 e = (f32x4)0.f;
#pragma unroll
    for (int kk = 0; kk < 6; ++kk) {
        short8 ah = *(const short8*)&Hs[(w * 16 + lm) * 200 + kk * 32 + (q << 3)];
        short8 bw = *(const short8*)(W2F + ((size_t)((half * 6 + kk) * 64 + lane)) * 8);
        e = __builtin_amdgcn_mfma_f32_16x16x32_bf16(ah, bw, e, 0, 0, 0);
    }
    if (lm < 9) {
        float* emo = half ? em1 : em0;
        const float badd = half ? 0.f : b2[lm];
#pragma unroll
        for (int r = 0; r < 4; ++r)
            emo[(size_t)(row0 + w * 16 + q * 4 + r) * T_ + lm] = e[r] + badd;
    }
}

// -----------------------------------------------------------------------------
// Kernel 2: CRF. 64 blocks x 640 threads.
// Phase A: threads 0..575 = (chunk c in [0,64), row i0) build 9x9 transfer
// matrices over 8 steps, trans in registers. Wave 9 (576..639) concurrently
// computes the numerator. Phase B: 6-level TREE combine of the 64 matrices
// (log-semiring matmul is associative). Final: alpha0 x M_total, logsumexp,
// atomicAdd of (denom-numer)/B into d_out (zeroed by prep).
// -----------------------------------------------------------------------------
__global__ __launch_bounds__(640) void crf_kernel(
    const float* __restrict__ em0,
    const float* __restrict__ em1,
    const int* __restrict__ labels,
    const unsigned char* __restrict__ maskb,
    const float* __restrict__ st,
    const float* __restrict__ et,
    const float* __restrict__ tr,
    float* __restrict__ out)
{
    const int b = blockIdx.x;
    const int t = threadIdx.x;

    __shared__ float es[64 * 73];    // es[c*73 + s*9 + j]
    __shared__ float Msa[64 * 81];
    __shared__ float Msb[32 * 81];
    __shared__ float trs[81];
    __shared__ float red_num;
    __shared__ unsigned char msh[L_];
    __shared__ int lbs[L_];

    const int mstride =
        (maskb[0] != 0 && maskb[1] == 0 && maskb[2] == 0 && maskb[3] == 0) ? 4 : 1;

    const float* e0 = em0 + (size_t)b * L_ * T_;
    const float* e1 = em1 + (size_t)b * L_ * T_;
    for (int i = t; i < L_ * T_; i += 640) {
        int tt = i / T_, j = i - tt * T_;
        es[(tt >> 3) * 73 + (tt & 7) * 9 + j] = e0[i] + e1[i];
    }
    if (t < 81) trs[t] = tr[t];
    for (int i = t; i < L_; i += 640) {
        msh[i] = maskb[((size_t)b * L_ + i) * (size_t)mstride];
        lbs[i] = labels[b * L_ + i];
    }
    __syncthreads();

    if (t < 576) {
        // ---- Phase A ----
        const int c  = t / 9;
        const int i0 = t - c * 9;
        float trr[81];
#pragma unroll
        for (int i = 0; i < 81; ++i) trr[i] = trs[i];
        float V[9];
#pragma unroll
        for (int j = 0; j < 9; ++j) V[j] = (j == i0) ? 0.f : -1e30f;

        const int sbeg = (c == 0) ? 1 : 0;
        for (int s = sbeg; s < 8; ++s) {
            int tt = c * 8 + s;
            if (msh[tt]) {
                const float* ep = &es[c * 73 + s * 9];
                float nv[9];
#pragma unroll
                for (int j = 0; j < 9; ++j) {
                    float a[9];
#pragma unroll
                    for (int k = 0; k < 9; ++k) a[k] = V[k] + trr[k * 9 + j];
                    float mx = a[0];
#pragma unroll
                    for (int k = 1; k < 9; ++k) mx = fmaxf(mx, a[k]);
                    float sum = 0.f;
#pragma unroll
                    for (int k = 0; k < 9; ++k) sum += __expf(a[k] - mx);
                    nv[j] = ep[j] + mx + __logf(sum);
                }
#pragma unroll
                for (int j = 0; j < 9; ++j) V[j] = nv[j];
            }
        }
#pragma unroll
        for (int j = 0; j < 9; ++j) Msa[c * 81 + i0 * 9 + j] = V[j];
    } else {
        // ---- numerator (wave 9, concurrent with Phase A) ----
        const int lane = t - 576;
        float emit_s = 0.f, tr_sc = 0.f, mcnt = 0.f;
        for (int tt = lane; tt < L_; tt += 64) {
            if (msh[tt]) {
                mcnt += 1.f;
                int tag = lbs[tt];
                emit_s += es[(tt >> 3) * 73 + (tt & 7) * 9 + tag];
                if (tt >= 1) tr_sc += trs[lbs[tt - 1] * 9 + tag];
            }
        }
        emit_s = wredf(emit_s);
        tr_sc  = wredf(tr_sc);
        mcnt   = wredf(mcnt);
        if (lane == 0) {
            int last = (int)mcnt - 1;
            red_num = st[lbs[0]] + emit_s + tr_sc + et[lbs[last]];
        }
    }
    __syncthreads();

    // ---- Phase B: tree combine, 6 levels ----
    float* src = Msa;
    float* dst = Msb;
    for (int n = 32; n >= 1; n >>= 1) {
        for (int idx = t; idx < n * 81; idx += 640) {
            int p = idx / 81;
            int r = idx - p * 81;
            int i = r / 9, j = r - i * 9;
            const float* A  = src + (2 * p) * 81 + i * 9;
            const float* Bm = src + (2 * p + 1) * 81 + j;
            float v[9];
#pragma unroll
            for (int k = 0; k < 9; ++k) v[k] = A[k] + Bm[k * 9];
            float mx = v[0];
#pragma unroll
            for (int k = 1; k < 9; ++k) mx = fmaxf(mx, v[k]);
            float sum = 0.f;
#pragma unroll
            for (int k = 0; k < 9; ++k) sum += __expf(v[k] - mx);
            dst[p * 81 + r] = mx + __logf(sum);
        }
        __syncthreads();
        float* tmp = src; src = dst; dst = tmp;
    }
    // final matrix in src (= Msa after 6 swaps)

    if (t < 64) {
        float v = -3.0e38f;
        if (t < 9) {
            float a[9];
#pragma unroll
            for (int i = 0; i < 9; ++i) a[i] = st[i] + es[i] + src[i * 9 + t];
            float mx = a[0];
#pragma unroll
            for (int i = 1; i < 9; ++i) mx = fmaxf(mx, a[i]);
            float sum = 0.f;
#pragma unroll
            for (int i = 0; i < 9; ++i) sum += __expf(a[i] - mx);
            v = mx + __logf(sum) + et[t];
        }
        float mx = v;
#pragma unroll
        for (int m = 32; m >= 1; m >>= 1) mx = fmaxf(mx, __shfl_xor(mx, m, 64));
        float sm = __expf(v - mx);
        sm = wredf(sm);
        if (t == 0) {
            float denom = mx + __logf(sm);
            atomicAdd(out, (denom - red_num) * (1.0f / (float)B_));
        }
    }
}

extern "C" void kernel_launch(void* const* d_in, const int* in_sizes, int n_in,
                              void* d_out, int out_size, void* d_ws, size_t ws_size,
                              hipStream_t stream) {
    const float*         enc    = (const float*)d_in[0];
    const int*           labels = (const int*)d_in[1];
    const unsigned char* mask   = (const unsigned char*)d_in[2];
    const float*         W1     = (const float*)d_in[3];
    const float*         b1     = (const float*)d_in[4];
    const float*         W2     = (const float*)d_in[5];
    const float*         b2     = (const float*)d_in[6];
    const float*         st     = (const float*)d_in[7];
    const float*         et     = (const float*)d_in[8];
    const float*         tr     = (const float*)d_in[9];

    float* em0          = (float*)d_ws;                        // 1,179,648 B
    float* em1          = em0 + (size_t)M_ * T_;               // 1,179,648 B
    unsigned short* W1F = (unsigned short*)(em1 + (size_t)M_ * T_);  // 589,824 B
    unsigned short* W2F = W1F + (size_t)576 * 64 * 8;          // 12,288 B

    prep_kernel<<<147, 256, 0, stream>>>(W1, W2, W1F, W2F, (float*)d_out);
    emis_mfma_kernel<<<1024, 256, 0, stream>>>(enc, W1F, b1, W2F, b2, em0, em1);
    crf_kernel<<<B_, 640, 0, stream>>>(em0, em1, labels, mask, st, et, tr, (float*)d_out);
}